// Round 4
// baseline (421.838 us; speedup 1.0000x reference)
//
#include <hip/hip_runtime.h>

#define B_ROWS 32768
#define NIN 41
#define NL2 4
#define NRC 8

// clamp via single v_med3_f32
__device__ __forceinline__ float med3(float v, float lo, float hi) {
    return __builtin_amdgcn_fmed3f(v, lo, hi);
}

// one DPP step: x += dpp(x, ctrl)
template <int Ctrl>
__device__ __forceinline__ int dpp_add(int x) {
    return __float_as_int(
        __int_as_float(x) +
        __int_as_float(__builtin_amdgcn_update_dpp(0, x, Ctrl, 0xf, 0xf, true)));
}

// full 64-lane sum via DPP (VALU pipe only), result wave-uniform (SGPR)
__device__ __forceinline__ float wave_sum_uniform(float v) {
    int x = __float_as_int(v);
    x = dpp_add<0x111>(x);  // row_shr:1
    x = dpp_add<0x112>(x);  // row_shr:2
    x = dpp_add<0x114>(x);  // row_shr:4
    x = dpp_add<0x118>(x);  // row_shr:8  -> lanes 15/31/47/63 hold row sums
    x = dpp_add<0x142>(x);  // row_bcast:15
    x = dpp_add<0x143>(x);  // row_bcast:31 -> lane 63 = total
    return __int_as_float(__builtin_amdgcn_readlane(x, 63));
}

__device__ __forceinline__ void blur8(float* v) {
    float t[NRC];
    #pragma unroll
    for (int r = 0; r < NRC; ++r) {
        float s = 0.8f * v[r];
        if (r > 0)       s += 0.1f * v[r - 1];
        if (r < NRC - 1) s += 0.1f * v[r + 1];
        t[r] = s;
    }
    #pragma unroll
    for (int r = 0; r < NRC; ++r) v[r] = t[r];
}

__device__ __forceinline__ void blur4(float* v) {
    float t[NL2];
    #pragma unroll
    for (int o = 0; o < NL2; ++o) {
        float s = 0.8f * v[o];
        if (o > 0)       s += 0.1f * v[o - 1];
        if (o < NL2 - 1) s += 0.1f * v[o + 1];
        t[o] = s;
    }
    #pragma unroll
    for (int o = 0; o < NL2; ++o) v[o] = t[o];
}

__global__ void __launch_bounds__(256, 8) pgnet_kernel(
    const float* __restrict__ inp,
    const float* __restrict__ fpg_w,
    const float* __restrict__ fpg_b,
    const float* __restrict__ rpg_w,
    const float* __restrict__ rpg_b,
    const float* __restrict__ pgw,   // [8,86]
    const float* __restrict__ pgb,   // [8]
    float* __restrict__ out)
{
    const int lane = threadIdx.x & 63;
    const int row  = blockIdx.x * 4 + (threadIdx.x >> 6);
    const bool act = lane < NIN;
    const int safe = act ? lane : (NIN - 1);   // in-bounds address for all lanes

    // ===== phase-1 loads: pgctrl + inp + fpg_w + biases (peak ~56 VGPR) =====
    const float x_raw = inp[row * NIN + safe];

    float w1r[NRC], w2r[NRC];
    #pragma unroll
    for (int r = 0; r < NRC; ++r) {
        w1r[r] = pgw[r * 86 + safe];
        w2r[r] = pgw[r * 86 + 45 + safe];
    }

    // fpg_w[b,o,i,r]: b*1312 + o*328 + i*8 + r
    const float* fp = fpg_w + (size_t)row * 1312 + (size_t)safe * 8;
    float4 fwv[NL2][2];
    #pragma unroll
    for (int o = 0; o < NL2; ++o) {
        fwv[o][0] = *(const float4*)(fp + o * 328);
        fwv[o][1] = *(const float4*)(fp + o * 328 + 4);
    }

    const float4 fbv  = *(const float4*)(fpg_b + (size_t)row * NL2); // wave-uniform
    const float  rb_r = rpg_b[row * NIN + safe];

    __builtin_amdgcn_sched_barrier(0);

    const float x  = act ? x_raw : 0.0f;
    const float rb = act ? rb_r  : 0.0f;

    // A[r] = pgb[r] + sum_i x_i*(W[r,i]+W[r,45+i])   (wave-uniform)
    float W2[NRC], A[NRC];
    #pragma unroll
    for (int r = 0; r < NRC; ++r) {
        A[r]  = wave_sum_uniform(x * (w1r[r] + w2r[r])) + pgb[r];
        W2[r] = act ? w2r[r] : 0.0f;   // per-lane, needed for iter-2 corr
    }

    // F[o][r] = sum_i x_i * clip(fpg_w)[o,i,r]   (wave-uniform; frees fwv)
    float F[NL2][NRC];
    #pragma unroll
    for (int o = 0; o < NL2; ++o) {
        const float f0 = x * med3(fwv[o][0].x, -1.f, 1.f);
        const float f1 = x * med3(fwv[o][0].y, -1.f, 1.f);
        const float f2 = x * med3(fwv[o][0].z, -1.f, 1.f);
        const float f3 = x * med3(fwv[o][0].w, -1.f, 1.f);
        const float f4 = x * med3(fwv[o][1].x, -1.f, 1.f);
        const float f5 = x * med3(fwv[o][1].y, -1.f, 1.f);
        const float f6 = x * med3(fwv[o][1].z, -1.f, 1.f);
        const float f7 = x * med3(fwv[o][1].w, -1.f, 1.f);
        F[o][0] = wave_sum_uniform(f0); F[o][1] = wave_sum_uniform(f1);
        F[o][2] = wave_sum_uniform(f2); F[o][3] = wave_sum_uniform(f3);
        F[o][4] = wave_sum_uniform(f4); F[o][5] = wave_sum_uniform(f5);
        F[o][6] = wave_sum_uniform(f6); F[o][7] = wave_sum_uniform(f7);
    }

    // ===== phase-2 loads: rpg_w issued now; latency overlapped w/ iter-1 math =====
    const float* rp = rpg_w + (size_t)row * 1312 + (size_t)safe * 32;
    float4 rwv[8];
    #pragma unroll
    for (int j = 0; j < 8; ++j) rwv[j] = ((const float4*)rp)[j];
    __builtin_amdgcn_sched_barrier(0);

    const float fb[NL2] = {fbv.x, fbv.y, fbv.z, fbv.w};

    // -------- iteration 1 (l1i == 0 -> no corr), all wave-uniform math --------
    float rcv[NRC];
    #pragma unroll
    for (int r = 0; r < NRC; ++r) {
        const float pre = A[r];
        const float v = (pre >= 0.f) ? pre : 0.2f * pre;
        rcv[r] = med3(0.4f * v, -0.2f, 1.0f);
    }
    blur8(rcv); blur8(rcv); blur8(rcv);

    float l2v[NL2];
    #pragma unroll
    for (int o = 0; o < NL2; ++o) {
        float s = fb[o];
        #pragma unroll
        for (int r = 0; r < NRC; ++r) s += F[o][r] * rcv[r];
        l2v[o] = med3(0.1f * s, -0.2f, 1.0f);
    }
    blur4(l2v); blur4(l2v);

    // consume rpg_w now (clamped once, reused in iter 2)
    float rw[NL2][NRC];
    #pragma unroll
    for (int o = 0; o < NL2; ++o) {
        rw[o][0] = med3(rwv[2*o].x, -1.f, 1.f);   rw[o][1] = med3(rwv[2*o].y, -1.f, 1.f);
        rw[o][2] = med3(rwv[2*o].z, -1.f, 1.f);   rw[o][3] = med3(rwv[2*o].w, -1.f, 1.f);
        rw[o][4] = med3(rwv[2*o+1].x, -1.f, 1.f); rw[o][5] = med3(rwv[2*o+1].y, -1.f, 1.f);
        rw[o][6] = med3(rwv[2*o+1].z, -1.f, 1.f); rw[o][7] = med3(rwv[2*o+1].w, -1.f, 1.f);
    }

    float l1;
    {
        float acc = rb;
        #pragma unroll
        for (int o = 0; o < NL2; ++o) {
            float d = 0.f;
            #pragma unroll
            for (int r = 0; r < NRC; ++r) d += rw[o][r] * rcv[r];
            acc += l2v[o] * d;
        }
        l1 = med3(acc, -0.2f, 1.0f);
    }

    // -------- iteration 2 --------
    #pragma unroll
    for (int r = 0; r < NRC; ++r) {
        const float pre = A[r] - wave_sum_uniform(l1 * W2[r]);
        const float v = (pre >= 0.f) ? pre : 0.2f * pre;
        rcv[r] = med3(0.4f * v, -0.2f, 1.0f);
    }
    blur8(rcv); blur8(rcv); blur8(rcv);

    #pragma unroll
    for (int o = 0; o < NL2; ++o) {
        float s = fb[o];
        #pragma unroll
        for (int r = 0; r < NRC; ++r) s += F[o][r] * rcv[r];
        l2v[o] = med3(0.1f * s, -0.2f, 1.0f);
    }
    blur4(l2v); blur4(l2v);

    {
        float acc = rb;
        #pragma unroll
        for (int o = 0; o < NL2; ++o) {
            float d = 0.f;
            #pragma unroll
            for (int r = 0; r < NRC; ++r) d += rw[o][r] * rcv[r];
            acc += l2v[o] * d;
        }
        l1 = med3(acc, -0.2f, 1.0f);
    }

    // ---------- stores: [l1i (B*41) | l2 (B*4) | rc (B*8)] ----------
    if (act) out[(size_t)row * NIN + lane] = l1;
    if (lane < NL2) {
        float v = l2v[0];
        #pragma unroll
        for (int o = 1; o < NL2; ++o) if (lane == o) v = l2v[o];
        out[(size_t)B_ROWS * NIN + (size_t)row * NL2 + lane] = v;
    }
    if (lane < NRC) {
        float v = rcv[0];
        #pragma unroll
        for (int r = 1; r < NRC; ++r) if (lane == r) v = rcv[r];
        out[(size_t)B_ROWS * (NIN + NL2) + (size_t)row * NRC + lane] = v;
    }
}

extern "C" void kernel_launch(void* const* d_in, const int* in_sizes, int n_in,
                              void* d_out, int out_size, void* d_ws, size_t ws_size,
                              hipStream_t stream) {
    const float* inp   = (const float*)d_in[0];
    const float* fpg_w = (const float*)d_in[1];
    const float* fpg_b = (const float*)d_in[2];
    const float* rpg_w = (const float*)d_in[3];
    const float* rpg_b = (const float*)d_in[4];
    const float* pgw   = (const float*)d_in[5];
    const float* pgb   = (const float*)d_in[6];
    float* out = (float*)d_out;

    dim3 grid(B_ROWS / 4);   // one wave per row
    dim3 block(256);
    hipLaunchKernelGGL(pgnet_kernel, grid, block, 0, stream,
                       inp, fpg_w, fpg_b, rpg_w, rpg_b, pgw, pgb, out);
}

// Round 5
// 358.032 us; speedup vs baseline: 1.1782x; 1.1782x over previous
//
#include <hip/hip_runtime.h>

#define B_ROWS 32768
#define NIN 41
#define NL2 4
#define NRC 8

// clamp via single v_med3_f32
__device__ __forceinline__ float med3(float v, float lo, float hi) {
    return __builtin_amdgcn_fmed3f(v, lo, hi);
}

// one DPP step: x += dpp(x, ctrl)
template <int Ctrl>
__device__ __forceinline__ int dpp_add(int x) {
    return __float_as_int(
        __int_as_float(x) +
        __int_as_float(__builtin_amdgcn_update_dpp(0, x, Ctrl, 0xf, 0xf, true)));
}

// full 64-lane sum via DPP (VALU pipe only), result wave-uniform (SGPR)
__device__ __forceinline__ float wave_sum_uniform(float v) {
    int x = __float_as_int(v);
    x = dpp_add<0x111>(x);  // row_shr:1
    x = dpp_add<0x112>(x);  // row_shr:2
    x = dpp_add<0x114>(x);  // row_shr:4
    x = dpp_add<0x118>(x);  // row_shr:8  -> lanes 15/31/47/63 hold row sums
    x = dpp_add<0x142>(x);  // row_bcast:15
    x = dpp_add<0x143>(x);  // row_bcast:31 -> lane 63 = total
    return __int_as_float(__builtin_amdgcn_readlane(x, 63));
}

__device__ __forceinline__ void blur8(float* v) {
    float t[NRC];
    #pragma unroll
    for (int r = 0; r < NRC; ++r) {
        float s = 0.8f * v[r];
        if (r > 0)       s += 0.1f * v[r - 1];
        if (r < NRC - 1) s += 0.1f * v[r + 1];
        t[r] = s;
    }
    #pragma unroll
    for (int r = 0; r < NRC; ++r) v[r] = t[r];
}

__device__ __forceinline__ void blur4(float* v) {
    float t[NL2];
    #pragma unroll
    for (int o = 0; o < NL2; ++o) {
        float s = 0.8f * v[o];
        if (o > 0)       s += 0.1f * v[o - 1];
        if (o < NL2 - 1) s += 0.1f * v[o + 1];
        t[o] = s;
    }
    #pragma unroll
    for (int o = 0; o < NL2; ++o) v[o] = t[o];
}

__global__ void __launch_bounds__(256, 4) pgnet_kernel(
    const float* __restrict__ inp,
    const float* __restrict__ fpg_w,
    const float* __restrict__ fpg_b,
    const float* __restrict__ rpg_w,
    const float* __restrict__ rpg_b,
    const float* __restrict__ pgw,   // [8,86]
    const float* __restrict__ pgb,   // [8]
    float* __restrict__ out)
{
    const int lane = threadIdx.x & 63;
    const int row  = blockIdx.x * 4 + (threadIdx.x >> 6);
    const bool act = lane < NIN;
    const int safe = act ? lane : (NIN - 1);   // in-bounds address for all lanes

    // ============ ALL loads issued up-front, one latency exposure ============
    const float x_raw = inp[row * NIN + safe];

    // fpg_w[b,o,i,r]: b*1312 + o*328 + i*8 + r
    const float* fp = fpg_w + (size_t)row * 1312 + (size_t)safe * 8;
    float4 fwv[NL2][2];
    #pragma unroll
    for (int o = 0; o < NL2; ++o) {
        fwv[o][0] = *(const float4*)(fp + o * 328);
        fwv[o][1] = *(const float4*)(fp + o * 328 + 4);
    }

    // rpg_w[b,i,o,r]: b*1312 + i*32 + o*8 + r  (32 contiguous floats per i)
    const float* rp = rpg_w + (size_t)row * 1312 + (size_t)safe * 32;
    float4 rwv[8];
    #pragma unroll
    for (int j = 0; j < 8; ++j) rwv[j] = ((const float4*)rp)[j];

    // pgctrl table (688 B, cache-resident)
    float w1r[NRC], w2r[NRC];
    #pragma unroll
    for (int r = 0; r < NRC; ++r) {
        w1r[r] = pgw[r * 86 + safe];
        w2r[r] = pgw[r * 86 + 45 + safe];
    }

    const float4 fbv  = *(const float4*)(fpg_b + (size_t)row * NL2); // wave-uniform
    const float  rb_r = rpg_b[row * NIN + safe];

    __builtin_amdgcn_sched_barrier(0);   // pin: all loads before any math
    // =========================================================================

    const float x  = act ? x_raw : 0.0f;
    const float rb = act ? rb_r  : 0.0f;

    // A[r] = pgb[r] + sum_i x_i*(W[r,i]+W[r,45+i])  (8 parallel reductions)
    float W2[NRC], A[NRC];
    #pragma unroll
    for (int r = 0; r < NRC; ++r) {
        A[r]  = wave_sum_uniform(x * (w1r[r] + w2r[r])) + pgb[r];
        W2[r] = act ? w2r[r] : 0.0f;
    }

    // clamp weights in place (junk lanes harmless: x=0 kills fw, W2=0 kills l1)
    float fw[NL2][NRC];
    #pragma unroll
    for (int o = 0; o < NL2; ++o) {
        fw[o][0] = med3(fwv[o][0].x, -1.f, 1.f); fw[o][1] = med3(fwv[o][0].y, -1.f, 1.f);
        fw[o][2] = med3(fwv[o][0].z, -1.f, 1.f); fw[o][3] = med3(fwv[o][0].w, -1.f, 1.f);
        fw[o][4] = med3(fwv[o][1].x, -1.f, 1.f); fw[o][5] = med3(fwv[o][1].y, -1.f, 1.f);
        fw[o][6] = med3(fwv[o][1].z, -1.f, 1.f); fw[o][7] = med3(fwv[o][1].w, -1.f, 1.f);
    }
    float rw[NL2][NRC];
    #pragma unroll
    for (int o = 0; o < NL2; ++o) {
        rw[o][0] = med3(rwv[2*o].x, -1.f, 1.f);   rw[o][1] = med3(rwv[2*o].y, -1.f, 1.f);
        rw[o][2] = med3(rwv[2*o].z, -1.f, 1.f);   rw[o][3] = med3(rwv[2*o].w, -1.f, 1.f);
        rw[o][4] = med3(rwv[2*o+1].x, -1.f, 1.f); rw[o][5] = med3(rwv[2*o+1].y, -1.f, 1.f);
        rw[o][6] = med3(rwv[2*o+1].z, -1.f, 1.f); rw[o][7] = med3(rwv[2*o+1].w, -1.f, 1.f);
    }

    const float fb[NL2] = {fbv.x, fbv.y, fbv.z, fbv.w};

    float l1, rcv[NRC], l2v[NL2];

    // ---------------- iteration 1 (l1i == 0 -> no corr) ----------------
    #pragma unroll
    for (int r = 0; r < NRC; ++r) {
        const float pre = A[r];
        const float v = (pre >= 0.f) ? pre : 0.2f * pre;
        rcv[r] = med3(0.4f * v, -0.2f, 1.0f);
    }
    blur8(rcv); blur8(rcv); blur8(rcv);

    // l2_pre[o] = sum_i x_i * (sum_r fw[o,i,r]*rc[r]) : per-lane dot, 1 reduction/o
    #pragma unroll
    for (int o = 0; o < NL2; ++o) {
        float d = 0.f;
        #pragma unroll
        for (int r = 0; r < NRC; ++r) d += fw[o][r] * rcv[r];
        const float s = wave_sum_uniform(x * d) + fb[o];
        l2v[o] = med3(0.1f * s, -0.2f, 1.0f);
    }
    blur4(l2v); blur4(l2v);

    {
        float acc = rb;
        #pragma unroll
        for (int o = 0; o < NL2; ++o) {
            float d = 0.f;
            #pragma unroll
            for (int r = 0; r < NRC; ++r) d += rw[o][r] * rcv[r];
            acc += l2v[o] * d;
        }
        l1 = med3(acc, -0.2f, 1.0f);
    }

    // ---------------- iteration 2 ----------------
    #pragma unroll
    for (int r = 0; r < NRC; ++r) {
        const float pre = A[r] - wave_sum_uniform(l1 * W2[r]);
        const float v = (pre >= 0.f) ? pre : 0.2f * pre;
        rcv[r] = med3(0.4f * v, -0.2f, 1.0f);
    }
    blur8(rcv); blur8(rcv); blur8(rcv);

    #pragma unroll
    for (int o = 0; o < NL2; ++o) {
        float d = 0.f;
        #pragma unroll
        for (int r = 0; r < NRC; ++r) d += fw[o][r] * rcv[r];
        const float s = wave_sum_uniform(x * d) + fb[o];
        l2v[o] = med3(0.1f * s, -0.2f, 1.0f);
    }
    blur4(l2v); blur4(l2v);

    {
        float acc = rb;
        #pragma unroll
        for (int o = 0; o < NL2; ++o) {
            float d = 0.f;
            #pragma unroll
            for (int r = 0; r < NRC; ++r) d += rw[o][r] * rcv[r];
            acc += l2v[o] * d;
        }
        l1 = med3(acc, -0.2f, 1.0f);
    }

    // ---------- stores: [l1i (B*41) | l2 (B*4) | rc (B*8)] ----------
    if (act) out[(size_t)row * NIN + lane] = l1;
    if (lane < NL2) {
        float v = l2v[0];
        #pragma unroll
        for (int o = 1; o < NL2; ++o) if (lane == o) v = l2v[o];
        out[(size_t)B_ROWS * NIN + (size_t)row * NL2 + lane] = v;
    }
    if (lane < NRC) {
        float v = rcv[0];
        #pragma unroll
        for (int r = 1; r < NRC; ++r) if (lane == r) v = rcv[r];
        out[(size_t)B_ROWS * (NIN + NL2) + (size_t)row * NRC + lane] = v;
    }
}

extern "C" void kernel_launch(void* const* d_in, const int* in_sizes, int n_in,
                              void* d_out, int out_size, void* d_ws, size_t ws_size,
                              hipStream_t stream) {
    const float* inp   = (const float*)d_in[0];
    const float* fpg_w = (const float*)d_in[1];
    const float* fpg_b = (const float*)d_in[2];
    const float* rpg_w = (const float*)d_in[3];
    const float* rpg_b = (const float*)d_in[4];
    const float* pgw   = (const float*)d_in[5];
    const float* pgb   = (const float*)d_in[6];
    float* out = (float*)d_out;

    dim3 grid(B_ROWS / 4);   // one wave per row
    dim3 block(256);
    hipLaunchKernelGGL(pgnet_kernel, grid, block, 0, stream,
                       inp, fpg_w, fpg_b, rpg_w, rpg_b, pgw, pgb, out);
}